// Round 10
// baseline (916.987 us; speedup 1.0000x reference)
//
#include <hip/hip_runtime.h>
#include <math.h>

// Kuramoto Euler, N=4096, 50 steps — PERSISTENT kernel, K lives in LDS.
// coupling_i = cos(th_i)*(K@sin th)_i - sin(th_i)*(K@cos th)_i
// 256 blocks x 512 thr (1 block/CU). Block b holds K rows [16b,16b+16) as
// bf16 in LDS (128 KiB) for the whole run -> K is read from HBM exactly
// once. Per step: thread t holds sc for cols [8t..8t+8) in registers;
// FMA over 16 rows (ds_read_b128 K); 3-level group butterfly + LDS scratch
// reduce; 16 row-owner threads update theta (exact adds) and rotate sc by
// a small-angle polynomial (validated r6-r8); new sc published to global
// (device-scope atomics) ; manual grid barrier (monotonic counter, zeroed
// by hipMemsetAsync each call -> graph-replay deterministic; capped spin
// so failure = wrong answer, never a hang).

#define NOSC 4096
#define NSTEPS 50
#define DTF 0.01f
#define NBLK 256
#define NTHR 512
#define ROWS 16                      // rows per block
#define CPT 8                        // cols per thread
#define KLDSB (ROWS * NOSC * 2)      // 131072 B
#define SCRB  (8 * 32 * 8 * 4)      // scr[w][v][g] = 8192 B
#define LDSB  (KLDSB + SCRB)         // 139264 B <= 160 KiB

__device__ __forceinline__ float bf_lo(unsigned int w) {
  return __uint_as_float(w << 16);
}
__device__ __forceinline__ float bf_hi(unsigned int w) {
  return __uint_as_float(w & 0xFFFF0000u);
}

extern "C" __global__ __launch_bounds__(NTHR, 2) void k_persist(
    const float* __restrict__ phases, const float* __restrict__ Kmat,
    const float* __restrict__ omegas, float* __restrict__ out,
    float2* __restrict__ scG, unsigned long long* __restrict__ cnt) {
  extern __shared__ unsigned char lds_raw[];
  unsigned short* K_lds = (unsigned short*)lds_raw;      // [16][4096] bf16
  float* scr = (float*)(lds_raw + KLDSB);                // [8][32][8]

  const int tid = threadIdx.x;
  const int lane = tid & 63;
  const int wv = tid >> 6;
  const int b = blockIdx.x;

  // ---- one-time: load K slice fp32 -> bf16 LDS (256 KiB coalesced)
  const float4* src =
      reinterpret_cast<const float4*>(Kmat + (size_t)b * ROWS * NOSC);
  #pragma unroll 4
  for (int q = 0; q < 32; ++q) {
    const int idx = q * NTHR + tid;            // float4 units, row-major
    const float4 f = src[idx];
    ushort4 o;
    unsigned int u;
    u = __float_as_uint(f.x); u += 0x7FFFu + ((u >> 16) & 1u); o.x = (unsigned short)(u >> 16);
    u = __float_as_uint(f.y); u += 0x7FFFu + ((u >> 16) & 1u); o.y = (unsigned short)(u >> 16);
    u = __float_as_uint(f.z); u += 0x7FFFu + ((u >> 16) & 1u); o.z = (unsigned short)(u >> 16);
    u = __float_as_uint(f.w); u += 0x7FFFu + ((u >> 16) & 1u); o.w = (unsigned short)(u >> 16);
    *reinterpret_cast<ushort4*>(&K_lds[idx * 4]) = o;
  }

  // ---- one-time: sc registers for own col slice; row-owner state
  float sreg[CPT], creg[CPT];
  #pragma unroll
  for (int i = 0; i < CPT; ++i) {
    const float ph = phases[CPT * tid + i];
    sreg[i] = sinf(ph);
    creg[i] = cosf(ph);
  }
  float thR = 0.f, omR = 0.f, sR = 0.f, cR = 0.f;
  if (tid < ROWS) {
    const int gi = b * ROWS + tid;
    thR = phases[gi];
    omR = omegas[gi];
    sR = sinf(thR);
    cR = cosf(thR);
  }
  __syncthreads();

  for (int step = 0; step < NSTEPS; ++step) {
    // ---- FMA phase: 16 rows x own 8 cols (K via contiguous ds_read_b128)
    float pS[ROWS], pC[ROWS];
    #pragma unroll
    for (int r = 0; r < ROWS; ++r) { pS[r] = 0.f; pC[r] = 0.f; }
    #pragma unroll
    for (int r = 0; r < ROWS; ++r) {
      const uint4 kw =
          *reinterpret_cast<const uint4*>(&K_lds[r * NOSC + CPT * tid]);
      float k;
      k = bf_lo(kw.x); pS[r] = fmaf(k, sreg[0], pS[r]); pC[r] = fmaf(k, creg[0], pC[r]);
      k = bf_hi(kw.x); pS[r] = fmaf(k, sreg[1], pS[r]); pC[r] = fmaf(k, creg[1], pC[r]);
      k = bf_lo(kw.y); pS[r] = fmaf(k, sreg[2], pS[r]); pC[r] = fmaf(k, creg[2], pC[r]);
      k = bf_hi(kw.y); pS[r] = fmaf(k, sreg[3], pS[r]); pC[r] = fmaf(k, creg[3], pC[r]);
      k = bf_lo(kw.z); pS[r] = fmaf(k, sreg[4], pS[r]); pC[r] = fmaf(k, creg[4], pC[r]);
      k = bf_hi(kw.z); pS[r] = fmaf(k, sreg[5], pS[r]); pC[r] = fmaf(k, creg[5], pC[r]);
      k = bf_lo(kw.w); pS[r] = fmaf(k, sreg[6], pS[r]); pC[r] = fmaf(k, creg[6], pC[r]);
      k = bf_hi(kw.w); pS[r] = fmaf(k, sreg[7], pS[r]); pC[r] = fmaf(k, creg[7], pC[r]);
    }

    // ---- reduce: 3-level butterfly within 8-lane groups (compile-time idx)
    #pragma unroll
    for (int off = 1; off <= 4; off <<= 1) {
      #pragma unroll
      for (int r = 0; r < ROWS; ++r) {
        pS[r] += __shfl_xor(pS[r], off);
        pC[r] += __shfl_xor(pC[r], off);
      }
    }
    // group leaders write: scr[wv][2r+comp][g]  (bank = (v*8+g)%32, g varies)
    if ((lane & 7) == 0) {
      const int g = lane >> 3;
      float* base = scr + wv * 256 + g;
      #pragma unroll
      for (int r = 0; r < ROWS; ++r) {
        base[(2 * r) * 8] = pS[r];
        base[(2 * r + 1) * 8] = pC[r];
      }
    }
    __syncthreads();

    // ---- row owners: final sum over (w,g), theta update, sc rotate, publish
    if (tid < ROWS) {
      float S = 0.f, C = 0.f;
      #pragma unroll
      for (int w = 0; w < 8; ++w) {
        const float4* p4 =
            reinterpret_cast<const float4*>(scr + w * 256 + 16 * tid);
        const float4 a = p4[0], bq = p4[1];   // v=2t : S over 8 groups
        const float4 c4 = p4[2], d4 = p4[3];  // v=2t+1 : C
        S += (a.x + a.y) + (a.z + a.w) + (bq.x + bq.y) + (bq.z + bq.w);
        C += (c4.x + c4.y) + (c4.z + c4.w) + (d4.x + d4.y) + (d4.z + d4.w);
      }
      const float delta = DTF * (omR + cR * S - sR * C);
      thR += delta;
      const float d2 = delta * delta;
      const float sd = delta * fmaf(d2, fmaf(d2, 1.f / 120.f, -1.f / 6.f), 1.f);
      const float cd = fmaf(d2, fmaf(d2, 1.f / 24.f, -0.5f), 1.f);
      const float ns = fmaf(sR, cd, cR * sd);
      const float nc = fmaf(cR, cd, -sR * sd);
      sR = ns;
      cR = nc;
      const unsigned long long bits =
          ((unsigned long long)__float_as_uint(nc) << 32) | __float_as_uint(ns);
      __hip_atomic_store((unsigned long long*)&scG[b * ROWS + tid], bits,
                         __ATOMIC_RELAXED, __HIP_MEMORY_SCOPE_AGENT);
    }
    if (step == NSTEPS - 1) break;   // no barrier after last step

    __syncthreads();                 // scG stores issued; scr safe to reuse
    if (tid == 0) {
      __threadfence();               // agent release: writeback L2
      __hip_atomic_fetch_add(cnt, 1ull, __ATOMIC_RELEASE,
                             __HIP_MEMORY_SCOPE_AGENT);
      const unsigned long long tgt = (unsigned long long)(step + 1) * NBLK;
      unsigned int spins = 0;
      while (__hip_atomic_load(cnt, __ATOMIC_ACQUIRE,
                               __HIP_MEMORY_SCOPE_AGENT) < tgt) {
        __builtin_amdgcn_s_sleep(2);
        if (++spins > (1u << 20)) break;   // failsafe: never hang the harness
      }
    }
    __syncthreads();

    // ---- reload own sc slice (atomic loads: bypass L1; L2 fresh via acquire)
    #pragma unroll
    for (int i = 0; i < CPT; ++i) {
      const unsigned long long bits = __hip_atomic_load(
          (const unsigned long long*)&scG[CPT * tid + i], __ATOMIC_RELAXED,
          __HIP_MEMORY_SCOPE_AGENT);
      sreg[i] = __uint_as_float((unsigned int)bits);
      creg[i] = __uint_as_float((unsigned int)(bits >> 32));
    }
  }

  if (tid < ROWS) out[b * ROWS + tid] = thR;
}

// ---- fallback: fp32 full-matrix streaming (round-3 structure)
__global__ __launch_bounds__(256) void k_init_fb(
    const float* __restrict__ phases, float* __restrict__ theta,
    float* __restrict__ svec, float* __restrict__ cvec) {
  const int i = blockIdx.x * 256 + threadIdx.x;
  const float t = phases[i];
  theta[i] = t;
  svec[i] = sinf(t);
  cvec[i] = cosf(t);
}

__global__ __launch_bounds__(256, 2) void k_step_full(
    const float* __restrict__ Kf, const float* __restrict__ omegas,
    float* __restrict__ theta,
    const float* __restrict__ s_in, const float* __restrict__ c_in,
    float* __restrict__ s_out, float* __restrict__ c_out) {
  const int lane = threadIdx.x & 63;
  const int wave = threadIdx.x >> 6;
  const int row0 = (blockIdx.x << 3) + (wave << 1);
  const int row1 = row0 + 1;
  const float4* s4 = reinterpret_cast<const float4*>(s_in);
  const float4* c4 = reinterpret_cast<const float4*>(c_in);
  const float4* K40 = reinterpret_cast<const float4*>(Kf + (size_t)row0 * NOSC);
  const float4* K41 = reinterpret_cast<const float4*>(Kf + (size_t)row1 * NOSC);
  float aS0 = 0.f, aC0 = 0.f, aS1 = 0.f, aC1 = 0.f;
  #pragma unroll
  for (int ch = 0; ch < 16; ++ch) {
    const int idx = (ch << 6) + lane;
    float4 k0 = K40[idx], k1 = K41[idx], sv = s4[idx], cv = c4[idx];
    aS0 = fmaf(k0.x, sv.x, aS0); aS0 = fmaf(k0.y, sv.y, aS0);
    aS0 = fmaf(k0.z, sv.z, aS0); aS0 = fmaf(k0.w, sv.w, aS0);
    aC0 = fmaf(k0.x, cv.x, aC0); aC0 = fmaf(k0.y, cv.y, aC0);
    aC0 = fmaf(k0.z, cv.z, aC0); aC0 = fmaf(k0.w, cv.w, aC0);
    aS1 = fmaf(k1.x, sv.x, aS1); aS1 = fmaf(k1.y, sv.y, aS1);
    aS1 = fmaf(k1.z, sv.z, aS1); aS1 = fmaf(k1.w, sv.w, aS1);
    aC1 = fmaf(k1.x, cv.x, aC1); aC1 = fmaf(k1.y, cv.y, aC1);
    aC1 = fmaf(k1.z, cv.z, aC1); aC1 = fmaf(k1.w, cv.w, aC1);
  }
  #pragma unroll
  for (int off = 32; off > 0; off >>= 1) {
    aS0 += __shfl_xor(aS0, off); aC0 += __shfl_xor(aC0, off);
    aS1 += __shfl_xor(aS1, off); aC1 += __shfl_xor(aC1, off);
  }
  const int myRow = (lane == 0) ? row0 : ((lane == 1) ? row1 : -1);
  if (myRow >= 0) {
    const float accS = (lane == 0) ? aS0 : aS1;
    const float accC = (lane == 0) ? aC0 : aC1;
    const float tn = theta[myRow] +
        DTF * (omegas[myRow] + c_in[myRow] * accS - s_in[myRow] * accC);
    theta[myRow] = tn;
    s_out[myRow] = sinf(tn);
    c_out[myRow] = cosf(tn);
  }
}

extern "C" void kernel_launch(void* const* d_in, const int* in_sizes, int n_in,
                              void* d_out, int out_size, void* d_ws, size_t ws_size,
                              hipStream_t stream) {
  const float* phases = (const float*)d_in[0];
  const float* Kmat   = (const float*)d_in[1];
  const float* omegas = (const float*)d_in[2];
  float* out = (float*)d_out;

  float2* scG = (float2*)d_ws;                                   // 32 KiB
  unsigned long long* cnt =
      (unsigned long long*)((char*)d_ws + (size_t)NOSC * 8);     // 8 B

  bool ok = (ws_size >= (size_t)NOSC * 8 + 64 + 6 * NOSC * 4);
  if (ok) {
    ok = (hipFuncSetAttribute((const void*)k_persist,
                              hipFuncAttributeMaxDynamicSharedMemorySize,
                              LDSB) == hipSuccess);
  }

  if (ok) {
    hipMemsetAsync(cnt, 0, sizeof(unsigned long long), stream);
    k_persist<<<NBLK, NTHR, LDSB, stream>>>(phases, Kmat, omegas, out, scG, cnt);
  } else {
    float* base = (float*)((char*)d_ws + (size_t)NOSC * 8 + 64);
    float* theta = base;
    float* sb[2] = {base + 1 * NOSC, base + 3 * NOSC};
    float* cb[2] = {base + 2 * NOSC, base + 4 * NOSC};
    k_init_fb<<<NOSC / 256, 256, 0, stream>>>(phases, theta, sb[0], cb[0]);
    for (int t = 0; t < NSTEPS; ++t) {
      k_step_full<<<NOSC / 8, 256, 0, stream>>>(
          Kmat, omegas, theta, sb[t & 1], cb[t & 1],
          sb[(t + 1) & 1], cb[(t + 1) & 1]);
    }
    hipMemcpyAsync(out, theta, NOSC * sizeof(float), hipMemcpyDeviceToDevice,
                   stream);
  }
}

// Round 11
// 307.792 us; speedup vs baseline: 2.9792x; 2.9792x over previous
//
#include <hip/hip_runtime.h>
#include <math.h>

// Kuramoto Euler, N=4096, 50 steps. K symmetry + atomic accumulators.
// coupling_i = cos(th_i)*(K@sin th)_i - sin(th_i)*(K@cos th)_i
// K -> bf16 upper-tri 128x128 tiles (528 tiles, 16.5 MiB/step).
// ONE kernel/step, 512 EQUAL blocks: 496 off-diag tiles (direct + transpose
// dots, register-blocked over an LDS tile) + 16 handler blocks owning TWO
// diagonal tiles each (2 x half-work = balanced) which also publish theta/sc
// for their 256 elements. Per-step combine via device-scope float atomicAdd
// into accS/accC[4096] (triple-buffered; each block zeroes its slice of the
// k+1 buffer). Phase 1 of every block: advance sc for its two panels from
// scPrev + accPrev (16B/element, no slot-reduce). Kernel boundary = barrier;
// no fences, no spin. Cross-launch visibility via stream ordering.

#define NOSC 4096
#define TILE 128
#define NPAN 32
#define NACT 528          // upper-tri tiles incl diagonal
#define NOFF 496          // strictly-upper tiles
#define NBLK 512          // 496 off-diag + 16 handlers
#define NSTEPS 50
#define DTF 0.01f
#define WP 66             // 32-bit words per LDS tile row

__device__ __forceinline__ float bf_lo(unsigned int w) {
  return __uint_as_float(w << 16);
}
__device__ __forceinline__ float bf_hi(unsigned int w) {
  return __uint_as_float(w & 0xFFFF0000u);
}
__device__ __forceinline__ unsigned short f2bf(float x) {
  unsigned int b = __float_as_uint(x);
  b += 0x7FFFu + ((b >> 16) & 1u);
  return (unsigned short)(b >> 16);
}
__device__ __forceinline__ int tri_offs(int bi) { return bi * (65 - bi) / 2; }
__device__ __forceinline__ int off_offs(int bi) { return bi * (63 - bi) / 2; }
__device__ __forceinline__ void off_decode(int t, int& bi, int& bj) {
  int b = (int)((63.0f - sqrtf(3969.0f - 8.0f * (float)t)) * 0.5f);
  if (b < 0) b = 0;
  while (b < NPAN - 1 && off_offs(b + 1) <= t) ++b;
  while (b > 0 && off_offs(b) > t) --b;
  bi = b;
  bj = b + 1 + (t - off_offs(b));
}

// tiles -> bf16; blocks 0..15 also init sc0; 16..47 zero acc buffer 0.
__global__ __launch_bounds__(256) void k_convert(
    const float* __restrict__ Kmat, unsigned short* __restrict__ Kt,
    const float* __restrict__ phases, float2* __restrict__ scInit,
    float* __restrict__ accS0, float* __restrict__ accC0) {
  const int t = blockIdx.x;
  const int tid = threadIdx.x;
  if (t < 16) {
    const int i = t * 256 + tid;
    const float ph = phases[i];
    scInit[i] = make_float2(sinf(ph), cosf(ph));
  } else if (t < 32) {
    accS0[(t - 16) * 256 + tid] = 0.f;
  } else if (t < 48) {
    accC0[(t - 32) * 256 + tid] = 0.f;
  }
  int bi = (int)((65.0f - sqrtf(4225.0f - 8.0f * (float)t)) * 0.5f);
  while (bi < NPAN - 1 && tri_offs(bi + 1) <= t) ++bi;
  while (bi > 0 && tri_offs(bi) > t) --bi;
  const int bj = bi + (t - tri_offs(bi));
  const float* src = Kmat + (size_t)(bi * TILE) * NOSC + (size_t)(bj * TILE);
  unsigned short* dst = Kt + (size_t)t * (TILE * TILE);
  #pragma unroll
  for (int q = 0; q < 16; ++q) {
    const int idx = q * 256 + tid;
    const int r = idx >> 5;
    const int c = (idx & 31) << 2;
    const float4 f = *reinterpret_cast<const float4*>(src + (size_t)r * NOSC + c);
    ushort4 o;
    o.x = f2bf(f.x); o.y = f2bf(f.y); o.z = f2bf(f.z); o.w = f2bf(f.w);
    *reinterpret_cast<ushort4*>(dst + r * TILE + c) = o;
  }
}

template <bool FIRST>
__global__ __launch_bounds__(256) void k_step(
    const unsigned short* __restrict__ Kt, const float* __restrict__ omegas,
    const float* __restrict__ thPrev, float* __restrict__ thNext,
    const float2* __restrict__ scPrev, float2* __restrict__ scNext,
    const float* __restrict__ accSp, const float* __restrict__ accCp,
    float* __restrict__ accSn, float* __restrict__ accCn,
    float* __restrict__ accSz, float* __restrict__ accCz) {
  __shared__ unsigned int tile_w[TILE * WP];   // 33792 B
  __shared__ float2 rowf[TILE], colf[TILE];
  __shared__ float2 dbuf[4][TILE];
  __shared__ float4 cbuf[4][32][2];
  __shared__ float2 scH[256];
  __shared__ float2 hbuf[256];

  const int b = blockIdx.x;
  const int tid = threadIdx.x;
  const int lane = tid & 63;
  const int wv = tid >> 6;
  const bool handler = (b >= NOFF);
  const int h = b - NOFF;
  int bi = 0, bj = 0;
  if (!handler) off_decode(b, bi, bj);

  // zero the (k+1) acc buffer slice (disjoint per block; safe: kernels serialize)
  if (tid < 8) accSz[b * 8 + tid] = 0.f;
  else if (tid < 16) accCz[b * 8 + (tid - 8)] = 0.f;

  // ---- phase 1: advance sc for this block's two panels (trig-free)
  {
    int i;
    if (handler) i = h * 256 + tid;
    else {
      const int half = tid >> 7;
      const int r = tid & 127;
      i = (half ? bj : bi) * TILE + r;
    }
    float2 sc = scPrev[i];
    if (!FIRST) {
      const float aS = accSp[i];
      const float aC = accCp[i];
      const float delta = DTF * (omegas[i] + sc.y * aS - sc.x * aC);
      const float d2 = delta * delta;
      const float sd = delta * fmaf(d2, fmaf(d2, 1.f / 120.f, -1.f / 6.f), 1.f);
      const float cd = fmaf(d2, fmaf(d2, 1.f / 24.f, -0.5f), 1.f);
      sc = make_float2(fmaf(sc.x, cd, sc.y * sd), fmaf(sc.y, cd, -sc.x * sd));
      if (handler) {
        thNext[i] = thPrev[i] + delta;
        scNext[i] = sc;
      }
    } else if (handler) {
      thNext[i] = thPrev[i];   // theta_0 = phases
      scNext[i] = sc;          // sc_0 = scInit
    }
    if (handler) scH[tid] = sc;
    else if (tid < 128) rowf[tid] = sc;      // panel bi
    else colf[tid - 128] = sc;               // panel bj
  }

  if (!handler) {
    // ---- stage off-diag tile
    const int tile_id = tri_offs(bi) + (bj - bi);
    const unsigned short* g = Kt + (size_t)tile_id * (TILE * TILE);
    #pragma unroll
    for (int q = 0; q < 8; ++q) {
      const int idx = q * 256 + tid;
      const uint4 u = *reinterpret_cast<const uint4*>(g + idx * 8);
      const int r = idx >> 4;
      const int cw = (idx & 15) << 2;
      unsigned int* dw = &tile_w[r * WP + cw];
      dw[0] = u.x; dw[1] = u.y; dw[2] = u.z; dw[3] = u.w;
    }
    __syncthreads();

    if (wv >= 2) {
      // DIRECT: rows {gq,gq+32,gq+64,gq+96} x 16-word quarter Q
      const int gq = lane & 31;
      const int Q = ((wv - 2) << 1) | (lane >> 5);
      const int wbase = Q * 16;
      float accS[4] = {0.f, 0.f, 0.f, 0.f};
      float accC[4] = {0.f, 0.f, 0.f, 0.f};
      #pragma unroll
      for (int i = 0; i < 8; ++i) {
        const int wc = wbase + 2 * i;
        const float4 cf01 = *reinterpret_cast<const float4*>(&colf[2 * wc]);
        const float4 cf23 = *reinterpret_cast<const float4*>(&colf[2 * wc + 2]);
        #pragma unroll
        for (int k = 0; k < 4; ++k) {
          const uint2 w =
              *reinterpret_cast<const uint2*>(&tile_w[(gq + 32 * k) * WP + wc]);
          const float k0 = bf_lo(w.x), k1 = bf_hi(w.x);
          const float k2 = bf_lo(w.y), k3 = bf_hi(w.y);
          accS[k] = fmaf(k0, cf01.x, accS[k]); accC[k] = fmaf(k0, cf01.y, accC[k]);
          accS[k] = fmaf(k1, cf01.z, accS[k]); accC[k] = fmaf(k1, cf01.w, accC[k]);
          accS[k] = fmaf(k2, cf23.x, accS[k]); accC[k] = fmaf(k2, cf23.y, accC[k]);
          accS[k] = fmaf(k3, cf23.z, accS[k]); accC[k] = fmaf(k3, cf23.w, accC[k]);
        }
      }
      #pragma unroll
      for (int k = 0; k < 4; ++k)
        dbuf[Q][gq + 32 * k] = make_float2(accS[k], accC[k]);
    } else {
      // TRANSPOSE: cols {4m..4m+3}, rows [wv*64+rp*32, +32)
      const int m = lane & 31;
      const int rp = lane >> 5;
      const int rbase = wv * 64 + rp * 32;
      float tS[4] = {0.f, 0.f, 0.f, 0.f};
      float tC[4] = {0.f, 0.f, 0.f, 0.f};
      #pragma unroll
      for (int t = 0; t < 16; ++t) {
        const int r0 = rbase + 2 * t;
        const float4 rf = *reinterpret_cast<const float4*>(&rowf[r0]);
        const uint2 w0 = *reinterpret_cast<const uint2*>(&tile_w[r0 * WP + 2 * m]);
        const uint2 w1 =
            *reinterpret_cast<const uint2*>(&tile_w[(r0 + 1) * WP + 2 * m]);
        const float a0 = bf_lo(w0.x), a1 = bf_hi(w0.x);
        const float a2 = bf_lo(w0.y), a3 = bf_hi(w0.y);
        const float b0 = bf_lo(w1.x), b1 = bf_hi(w1.x);
        const float b2 = bf_lo(w1.y), b3 = bf_hi(w1.y);
        tS[0] = fmaf(a0, rf.x, tS[0]); tC[0] = fmaf(a0, rf.y, tC[0]);
        tS[1] = fmaf(a1, rf.x, tS[1]); tC[1] = fmaf(a1, rf.y, tC[1]);
        tS[2] = fmaf(a2, rf.x, tS[2]); tC[2] = fmaf(a2, rf.y, tC[2]);
        tS[3] = fmaf(a3, rf.x, tS[3]); tC[3] = fmaf(a3, rf.y, tC[3]);
        tS[0] = fmaf(b0, rf.z, tS[0]); tC[0] = fmaf(b0, rf.w, tC[0]);
        tS[1] = fmaf(b1, rf.z, tS[1]); tC[1] = fmaf(b1, rf.w, tC[1]);
        tS[2] = fmaf(b2, rf.z, tS[2]); tC[2] = fmaf(b2, rf.w, tC[2]);
        tS[3] = fmaf(b3, rf.z, tS[3]); tC[3] = fmaf(b3, rf.w, tC[3]);
      }
      const int set = wv * 2 + rp;
      cbuf[set][m][0] = make_float4(tS[0], tC[0], tS[1], tC[1]);
      cbuf[set][m][1] = make_float4(tS[2], tC[2], tS[3], tC[3]);
    }
    __syncthreads();

    // ---- combine + atomicAdd into acc (device-scope, no fences needed)
    if (wv >= 2) {
      const int r = (wv - 2) * 64 + lane;
      const float2 d0 = dbuf[0][r], d1 = dbuf[1][r];
      const float2 d2 = dbuf[2][r], d3 = dbuf[3][r];
      atomicAdd(&accSn[bi * TILE + r], (d0.x + d1.x) + (d2.x + d3.x));
      atomicAdd(&accCn[bi * TILE + r], (d0.y + d1.y) + (d2.y + d3.y));
    } else if (wv == 0) {
      const int m = lane & 31;
      const int hh = lane >> 5;
      const float4 c0 = cbuf[0][m][hh], c1 = cbuf[1][m][hh];
      const float4 c2 = cbuf[2][m][hh], c3 = cbuf[3][m][hh];
      const int c = bj * TILE + 4 * m + 2 * hh;
      atomicAdd(&accSn[c], (c0.x + c1.x) + (c2.x + c3.x));
      atomicAdd(&accCn[c], (c0.y + c1.y) + (c2.y + c3.y));
      atomicAdd(&accSn[c + 1], (c0.z + c1.z) + (c2.z + c3.z));
      atomicAdd(&accCn[c + 1], (c0.w + c1.w) + (c2.w + c3.w));
    }
  } else {
    // ---- handler: two diagonal tiles, sequential, full-tile direct dot
    #pragma unroll
    for (int q = 0; q < 2; ++q) {
      const int p = 2 * h + q;
      const unsigned short* g =
          Kt + (size_t)tri_offs(p) * (TILE * TILE);
      #pragma unroll
      for (int s = 0; s < 8; ++s) {
        const int idx = s * 256 + tid;
        const uint4 u = *reinterpret_cast<const uint4*>(g + idx * 8);
        const int r = idx >> 4;
        const int cw = (idx & 15) << 2;
        unsigned int* dw = &tile_w[r * WP + cw];
        dw[0] = u.x; dw[1] = u.y; dw[2] = u.z; dw[3] = u.w;
      }
      __syncthreads();

      const int r = tid & 127;
      const int half = tid >> 7;
      const unsigned int* tp = &tile_w[r * WP + half * 32];
      const float2* scp = &scH[q * 128 + half * 64];
      float pS = 0.f, pC = 0.f;
      #pragma unroll
      for (int c2 = 0; c2 < 32; ++c2) {
        const unsigned int w = tp[c2];
        const float2 f0 = scp[2 * c2];
        const float2 f1 = scp[2 * c2 + 1];
        pS = fmaf(bf_lo(w), f0.x, pS); pC = fmaf(bf_lo(w), f0.y, pC);
        pS = fmaf(bf_hi(w), f1.x, pS); pC = fmaf(bf_hi(w), f1.y, pC);
      }
      hbuf[tid] = make_float2(pS, pC);
      __syncthreads();
      if (tid < 128) {
        const float2 t0 = hbuf[tid];
        const float2 t1 = hbuf[128 + tid];
        atomicAdd(&accSn[p * TILE + tid], t0.x + t1.x);
        atomicAdd(&accCn[p * TILE + tid], t0.y + t1.y);
      }
      __syncthreads();   // tile_w/hbuf safe to reuse for q=1
    }
  }
}

__global__ __launch_bounds__(256) void k_final(
    const float* __restrict__ thPrev, const float2* __restrict__ scPrev,
    const float* __restrict__ accS, const float* __restrict__ accC,
    const float* __restrict__ omegas, float* __restrict__ out) {
  const int i = blockIdx.x * 256 + threadIdx.x;
  const float2 sc = scPrev[i];
  out[i] = thPrev[i] + DTF * (omegas[i] + sc.y * accS[i] - sc.x * accC[i]);
}

// ---- fallback (ws too small): fp32 full-matrix streaming (round-3 form)
__global__ __launch_bounds__(256) void k_init_fb(
    const float* __restrict__ phases, float* __restrict__ theta,
    float* __restrict__ svec, float* __restrict__ cvec) {
  const int i = blockIdx.x * 256 + threadIdx.x;
  const float t = phases[i];
  theta[i] = t;
  svec[i] = sinf(t);
  cvec[i] = cosf(t);
}

__global__ __launch_bounds__(256, 2) void k_step_full(
    const float* __restrict__ Kf, const float* __restrict__ omegas,
    float* __restrict__ theta,
    const float* __restrict__ s_in, const float* __restrict__ c_in,
    float* __restrict__ s_out, float* __restrict__ c_out) {
  const int lane = threadIdx.x & 63;
  const int wave = threadIdx.x >> 6;
  const int row0 = (blockIdx.x << 3) + (wave << 1);
  const int row1 = row0 + 1;
  const float4* s4 = reinterpret_cast<const float4*>(s_in);
  const float4* c4 = reinterpret_cast<const float4*>(c_in);
  const float4* K40 = reinterpret_cast<const float4*>(Kf + (size_t)row0 * NOSC);
  const float4* K41 = reinterpret_cast<const float4*>(Kf + (size_t)row1 * NOSC);
  float aS0 = 0.f, aC0 = 0.f, aS1 = 0.f, aC1 = 0.f;
  #pragma unroll
  for (int ch = 0; ch < 16; ++ch) {
    const int idx = (ch << 6) + lane;
    float4 k0 = K40[idx], k1 = K41[idx], sv = s4[idx], cv = c4[idx];
    aS0 = fmaf(k0.x, sv.x, aS0); aS0 = fmaf(k0.y, sv.y, aS0);
    aS0 = fmaf(k0.z, sv.z, aS0); aS0 = fmaf(k0.w, sv.w, aS0);
    aC0 = fmaf(k0.x, cv.x, aC0); aC0 = fmaf(k0.y, cv.y, aC0);
    aC0 = fmaf(k0.z, cv.z, aC0); aC0 = fmaf(k0.w, cv.w, aC0);
    aS1 = fmaf(k1.x, sv.x, aS1); aS1 = fmaf(k1.y, sv.y, aS1);
    aS1 = fmaf(k1.z, sv.z, aS1); aS1 = fmaf(k1.w, sv.w, aS1);
    aC1 = fmaf(k1.x, cv.x, aC1); aC1 = fmaf(k1.y, cv.y, aC1);
    aC1 = fmaf(k1.z, cv.z, aC1); aC1 = fmaf(k1.w, cv.w, aC1);
  }
  #pragma unroll
  for (int off = 32; off > 0; off >>= 1) {
    aS0 += __shfl_xor(aS0, off); aC0 += __shfl_xor(aC0, off);
    aS1 += __shfl_xor(aS1, off); aC1 += __shfl_xor(aC1, off);
  }
  const int myRow = (lane == 0) ? row0 : ((lane == 1) ? row1 : -1);
  if (myRow >= 0) {
    const float accS = (lane == 0) ? aS0 : aS1;
    const float accC = (lane == 0) ? aC0 : aC1;
    const float tn = theta[myRow] +
        DTF * (omegas[myRow] + c_in[myRow] * accS - s_in[myRow] * accC);
    theta[myRow] = tn;
    s_out[myRow] = sinf(tn);
    c_out[myRow] = cosf(tn);
  }
}

extern "C" void kernel_launch(void* const* d_in, const int* in_sizes, int n_in,
                              void* d_out, int out_size, void* d_ws, size_t ws_size,
                              hipStream_t stream) {
  const float* phases = (const float*)d_in[0];
  const float* Kmat   = (const float*)d_in[1];
  const float* omegas = (const float*)d_in[2];
  float* out = (float*)d_out;

  float* ws = (float*)d_ws;
  float2* scInit = (float2*)ws;                      // 4096 float2
  float2* scB[2] = {scInit + NOSC, scInit + 2 * NOSC};
  float* thB[2]  = {ws + 6 * NOSC, ws + 7 * NOSC};
  float* accS[3] = {ws + 8 * NOSC, ws + 9 * NOSC, ws + 10 * NOSC};
  float* accC[3] = {ws + 11 * NOSC, ws + 12 * NOSC, ws + 13 * NOSC};

  const size_t headBytes = (size_t)14 * NOSC * sizeof(float);
  const size_t ktOff = (headBytes + 255) & ~(size_t)255;
  const size_t ktBytes = (size_t)NACT * TILE * TILE * 2;   // 16.5 MiB
  const bool useTiles = (ws_size >= ktOff + ktBytes);
  unsigned short* Kt = (unsigned short*)((char*)d_ws + ktOff);

  if (useTiles) {
    k_convert<<<NACT, 256, 0, stream>>>(Kmat, Kt, phases, scInit,
                                        accS[0], accC[0]);
    for (int k = 0; k < NSTEPS; ++k) {
      const float2* scP = (k == 0) ? scInit : scB[(k - 1) & 1];
      float2* scN = scB[k & 1];
      const float* thP = (k == 0) ? phases : thB[(k - 1) & 1];
      float* thN = thB[k & 1];
      const int ip = (k + 2) % 3;     // prev (unused when k==0)
      const int in_ = k % 3;          // accumulate target
      const int iz = (k + 1) % 3;     // zero target
      if (k == 0) {
        k_step<true><<<NBLK, 256, 0, stream>>>(
            Kt, omegas, thP, thN, scP, scN, accS[ip], accC[ip],
            accS[in_], accC[in_], accS[iz], accC[iz]);
      } else {
        k_step<false><<<NBLK, 256, 0, stream>>>(
            Kt, omegas, thP, thN, scP, scN, accS[ip], accC[ip],
            accS[in_], accC[in_], accS[iz], accC[iz]);
      }
    }
    const int kl = NSTEPS - 1;
    k_final<<<NOSC / 256, 256, 0, stream>>>(
        thB[kl & 1], scB[kl & 1], accS[kl % 3], accC[kl % 3], omegas, out);
  } else {
    float* theta = ws;
    float* sb[2] = {ws + 1 * NOSC, ws + 3 * NOSC};
    float* cb[2] = {ws + 2 * NOSC, ws + 4 * NOSC};
    k_init_fb<<<NOSC / 256, 256, 0, stream>>>(phases, theta, sb[0], cb[0]);
    for (int t = 0; t < NSTEPS; ++t) {
      k_step_full<<<NOSC / 8, 256, 0, stream>>>(
          Kmat, omegas, theta, sb[t & 1], cb[t & 1],
          sb[(t + 1) & 1], cb[(t + 1) & 1]);
    }
    hipMemcpyAsync(out, theta, NOSC * sizeof(float), hipMemcpyDeviceToDevice,
                   stream);
  }
}